// Round 8
// baseline (172.362 us; speedup 1.0000x reference)
//
#include <hip/hip_runtime.h>
#include <math.h>

#define DD 8
#define ZD 16
#define HID 200
#define EPSL 0.1f
#define BS 16          // samples per block
#define NTHREADS 1024  // 16 waves: 4 waves/SIMD (hard VGPR cap 128)
#define NKC 7          // K chunks of 32 (200 -> 224)
#define NMT 13         // unit tiles of 16 (200 -> 208)
#define XSTR 216       // halfs per X row
#define CSTR 212       // halfs per coeff row
#define HSTR 20        // floats per Hr/gsh row
#define WSTR 208       // halfs per staged-weight row
#define NTAN 8
#define NT8 8          // n-tiles per wave in T phase (all tangents)

#define KSC 1024.0f        // backward-chain scale
#define SSC 64.0f          // tangent-chain scale
#define INV_K (1.0f/1024.0f)
#define INV_KS (1.0f/65536.0f)

typedef _Float16 half8 __attribute__((ext_vector_type(8)));
typedef _Float16 half4v __attribute__((ext_vector_type(4)));
typedef _Float16 half2v __attribute__((ext_vector_type(2)));
typedef float float4v __attribute__((ext_vector_type(4)));

#define S4 (NKC*NMT*64*8)
#define OFF_W1T 0
#define OFF_W2T (S4)
#define OFF_W1  (2*S4)
#define OFF_W2  (3*S4)
#define OFF_W0T (4*S4)
#define OFF_W0  (4*S4 + NMT*64*8)
#define WS_HALFS (4*S4 + NMT*64*8 + NKC*64*8)

// ---------------------------------------------------------------------------
__global__ void prep(const float* __restrict__ W0, const float* __restrict__ W1,
                     const float* __restrict__ W2, _Float16* __restrict__ ws)
{
    int idx = blockIdx.x * 256 + threadIdx.x;
    if (idx >= WS_HALFS) return;
    float v = 0.f;
    if (idx < 4*S4) {
        int arr = idx / S4, e = idx % S4;
        int kc = e / (NMT*64*8); int r = e % (NMT*64*8);
        int mt = r / (64*8); r %= 64*8;
        int lane = r / 8, j = r % 8;
        int m = mt*16 + (lane & 15);
        int k = kc*32 + (lane >> 4)*8 + j;
        if (m < HID && k < HID) {
            if      (arr == 0) v = W1[k*HID + m];
            else if (arr == 1) v = W2[k*HID + m];
            else if (arr == 2) v = W1[m*HID + k];
            else               v = W2[m*HID + k];
        }
    } else if (idx < OFF_W0) {
        int e = idx - OFF_W0T;
        int mt = e / (64*8); int r = e % (64*8);
        int lane = r / 8, j = r % 8;
        int m = mt*16 + (lane & 15);
        int k = (lane >> 4)*8 + j;
        if (m < HID && k < ZD) v = W0[k*HID + m];
    } else {
        int e = idx - OFF_W0;
        int kc = e / (64*8); int r = e % (64*8);
        int lane = r / 8, j = r % 8;
        int m = (lane & 15);
        int k = kc*32 + (lane >> 4)*8 + j;
        if (k < HID) v = W0[m*HID + k];
    }
    ws[idx] = (_Float16)v;
}

// ---------------------------------------------------------------------------
__device__ __forceinline__ half4v pk4(float4v a) {
    half2v lo = __builtin_bit_cast(half2v, __builtin_amdgcn_cvt_pkrtz(a.x, a.y));
    half2v hi = __builtin_bit_cast(half2v, __builtin_amdgcn_cvt_pkrtz(a.z, a.w));
    return __builtin_shufflevector(lo, hi, 0, 1, 2, 3);
}
__device__ __forceinline__ void sig_sp(float x, float& sp, float& sg) {
    float e = __expf(-fabsf(x));
    float r = 1.0f / (1.0f + e);
    sg = (x >= 0.f) ? r : (1.0f - r);
    sp = fmaxf(x, 0.f) + __logf(1.f + e);
}

// Matvec over 7 K-chunks. MTC m-tiles x NTILES n-tiles. A rolling-prefetch
// depth 2 (NKC for the single-tile F phase); kc fully unrolled so the
// compiler can hoist ds_reads under the VGPR cap.
template<int NTILES, int MTC>
__device__ __forceinline__ void run_mv(const half8* __restrict__ Asw,
                                       const _Float16* __restrict__ Xsrc,
                                       int mt0, int lane,
                                       float4v acc[MTC][NTILES])
{
    const int lm = lane & 15, q = lane >> 4;
    constexpr int PF = (NTILES > 1) ? 2 : NKC;
#pragma unroll
    for (int m = 0; m < MTC; ++m)
#pragma unroll
        for (int n = 0; n < NTILES; ++n)
            acc[m][n] = (float4v){0.f, 0.f, 0.f, 0.f};

    half8 a[MTC][PF];
#pragma unroll
    for (int p = 0; p < PF; ++p)
#pragma unroll
        for (int m = 0; m < MTC; ++m)
            a[m][p] = Asw[(p*NMT + mt0 + m)*64 + lane];

#pragma unroll
    for (int kc = 0; kc < NKC; ++kc) {
        half8 x[NTILES];
#pragma unroll
        for (int n = 0; n < NTILES; ++n)
            x[n] = *(const half8*)(Xsrc + (n*16 + lm)*XSTR + kc*32 + q*8);
        half8 an[MTC];
        if (kc + PF < NKC)
#pragma unroll
            for (int m = 0; m < MTC; ++m)
                an[m] = Asw[((kc+PF)*NMT + mt0 + m)*64 + lane];
#pragma unroll
        for (int m = 0; m < MTC; ++m)
#pragma unroll
            for (int n = 0; n < NTILES; ++n)
                acc[m][n] = __builtin_amdgcn_mfma_f32_16x16x32_f16(a[m][0], x[n], acc[m][n], 0, 0, 0);
#pragma unroll
        for (int m = 0; m < MTC; ++m)
#pragma unroll
            for (int p = 0; p + 1 < PF; ++p) a[m][p] = a[m][p+1];
        if (kc + PF < NKC)
#pragma unroll
            for (int m = 0; m < MTC; ++m) a[m][PF-1] = an[m];
    }
}

// ---------------------------------------------------------------------------
__global__ void __launch_bounds__(NTHREADS, 4)
lnn_main(const float* __restrict__ z,
         const float* __restrict__ W0, const float* __restrict__ b0,
         const float* __restrict__ b1, const float* __restrict__ b2,
         const float* __restrict__ W3,
         const _Float16* __restrict__ ws,
         float* __restrict__ out)
{
    // Layout order matters: row-overrun reads (kc=6,q=3 spills 8 halfs past a
    // row) land in the next array; every such target is written-finite before
    // any read, and A=0 at k>=200 nullifies the products.
    __shared__ alignas(16) _Float16 Xt[128*XSTR];
    __shared__ alignas(16) _Float16 Xb[128*XSTR];
    __shared__ alignas(16) _Float16 Cf[5][16*CSTR]; // 0:p0 1:p1 2:c2*K 3:u1'(1-p1) 4:u0'p0(1-p0)
    __shared__ alignas(16) _Float16 Xz[16*40];
    __shared__ alignas(16) _Float16 bsh[4*WSTR];    // b0,b1,b2,KSC*W3 (zero-padded)
    __shared__ alignas(16) _Float16 w0t[NTAN*WSTR]; // SSC*W0[8+t][u] (zero-padded)
    __shared__ alignas(16) float gsh[16*HSTR];
    __shared__ alignas(16) float Hr[128*HSTR];

    const int tid  = threadIdx.x;
    const int wave = tid >> 6;
    const int lane = tid & 63;
    const int lm   = lane & 15;
    const int q    = lane >> 4;
    const int s0   = blockIdx.x * BS;

    const half8* W1Tsw = (const half8*)(ws + OFF_W1T);
    const half8* W2Tsw = (const half8*)(ws + OFF_W2T);
    const half8* W1sw  = (const half8*)(ws + OFF_W1);
    const half8* W2sw  = (const half8*)(ws + OFF_W2);
    const half8* W0Tsw = (const half8*)(ws + OFF_W0T);
    const half8* W0sw  = (const half8*)(ws + OFF_W0);

    // ---- init/staging ----
    if (tid < 256) {
        int s = tid >> 4, k = tid & 15;
        Xz[s*40 + k]      = (_Float16)z[(s0 + s)*ZD + k];
        Xz[s*40 + 16 + k] = (_Float16)0.f;
    }
    for (int idx = tid; idx < 128*16; idx += NTHREADS) {
        int r = idx >> 4, c = 200 + (idx & 15);
        Xt[r*XSTR + c] = (_Float16)0.f;
        Xb[r*XSTR + c] = (_Float16)0.f;
    }
    // F-phase row-15 fragment reads overrun into row 16 cols 0..7: zero once.
    if (tid < 8) {
        Xt[16*XSTR + tid] = (_Float16)0.f;
        Xb[16*XSTR + tid] = (_Float16)0.f;
    }
    for (int idx = tid; idx < 4*WSTR; idx += NTHREADS) {
        int l = idx / WSTR, u = idx % WSTR;
        float v = 0.f;
        if (u < HID) {
            if      (l == 0) v = b0[u];
            else if (l == 1) v = b1[u];
            else if (l == 2) v = b2[u];
            else             v = KSC * W3[u];
        }
        bsh[idx] = (_Float16)v;
    }
    for (int idx = tid; idx < NTAN*WSTR; idx += NTHREADS) {
        int t = idx / WSTR, u = idx % WSTR;
        w0t[idx] = (_Float16)((u < HID) ? SSC * W0[(DD + t)*HID + u] : 0.f);
    }
    __syncthreads();

    float4v acc1[1][1];
    const int ubf = wave*16 + q*4;   // F-phase unit base (wave<13)

    // ========== F-phase: ping-pong Xt/Xb, one barrier per stage ==========
    // F0: a0 = z@W0+b0 ; h0->Xt, p0->Cf0
    if (wave < NMT) {
        acc1[0][0] = (float4v){0.f,0.f,0.f,0.f};
        half8 xz = *(const half8*)(Xz + lm*40 + q*8);
        half8 a = W0Tsw[wave*64 + lane];
        acc1[0][0] = __builtin_amdgcn_mfma_f32_16x16x32_f16(a, xz, acc1[0][0], 0, 0, 0);
        half4v bb = *(const half4v*)(&bsh[0*WSTR + ubf]);
        float h[4], p[4];
#pragma unroll
        for (int r = 0; r < 4; ++r) {
            float av = acc1[0][0][r] + (float)bb[r];
            sig_sp(av, h[r], p[r]);
        }
        *(half4v*)(&Xt[lm*XSTR + ubf])     = pk4((float4v){h[0],h[1],h[2],h[3]});
        *(half4v*)(&Cf[0][lm*CSTR + ubf])  = pk4((float4v){p[0],p[1],p[2],p[3]});
    }
    __syncthreads();

    // F1: reads Xt(h0) -> h1->Xb, p1->Cf1   (write buffer != read buffer)
    if (wave < NMT) {
        run_mv<1,1>(W1Tsw, Xt, wave, lane, acc1);
        half4v bb = *(const half4v*)(&bsh[1*WSTR + ubf]);
        float h[4], p[4];
#pragma unroll
        for (int r = 0; r < 4; ++r) {
            float av = acc1[0][0][r] + (float)bb[r];
            sig_sp(av, h[r], p[r]);
        }
        *(half4v*)(&Xb[lm*XSTR + ubf])    = pk4((float4v){h[0],h[1],h[2],h[3]});
        *(half4v*)(&Cf[1][lm*CSTR + ubf]) = pk4((float4v){p[0],p[1],p[2],p[3]});
    }
    __syncthreads();

    // F2: reads Xb(h1) -> d2'->Xt, c2'->Cf2
    if (wave < NMT) {
        run_mv<1,1>(W2Tsw, Xb, wave, lane, acc1);
        half4v bb = *(const half4v*)(&bsh[2*WSTR + ubf]);
        half4v w3 = *(const half4v*)(&bsh[3*WSTR + ubf]);
        float d2[4], c2[4];
#pragma unroll
        for (int r = 0; r < 4; ++r) {
            float av = acc1[0][0][r] + (float)bb[r];
            float e = __expf(-fabsf(av));
            float rr = 1.f / (1.f + e);
            float sg = (av >= 0.f) ? rr : (1.f - rr);
            float wk = (float)w3[r];
            d2[r] = wk * sg;
            c2[r] = wk * sg * (1.f - sg);
        }
        *(half4v*)(&Xt[lm*XSTR + ubf])    = pk4((float4v){d2[0],d2[1],d2[2],d2[3]});
        *(half4v*)(&Cf[2][lm*CSTR + ubf]) = pk4((float4v){c2[0],c2[1],c2[2],c2[3]});
    }
    __syncthreads();

    // B1: reads Xt(d2') -> d1'->Xb, Cf3=u1'(1-p1)
    if (wave < NMT) {
        run_mv<1,1>(W2sw, Xt, wave, lane, acc1);
        half4v p1 = *(const half4v*)(&Cf[1][lm*CSTR + ubf]);
        half4v u1 = pk4(acc1[0][0]);
        half4v one = {(_Float16)1.f,(_Float16)1.f,(_Float16)1.f,(_Float16)1.f};
        *(half4v*)(&Xb[lm*XSTR + ubf])    = u1 * p1;
        *(half4v*)(&Cf[3][lm*CSTR + ubf]) = u1 * (one - p1);
    }
    __syncthreads();

    // B0: reads Xb(d1') -> d0'->Xt, Cf4=u0'p0(1-p0)
    if (wave < NMT) {
        run_mv<1,1>(W1sw, Xb, wave, lane, acc1);
        half4v p0 = *(const half4v*)(&Cf[0][lm*CSTR + ubf]);
        half4v u0 = pk4(acc1[0][0]);
        half4v one = {(_Float16)1.f,(_Float16)1.f,(_Float16)1.f,(_Float16)1.f};
        half4v d0 = u0 * p0;
        *(half4v*)(&Xt[lm*XSTR + ubf])    = d0;
        *(half4v*)(&Cf[4][lm*CSTR + ubf]) = d0 * (one - p0);
    }
    __syncthreads();

    // ===== g-projection (wave 0, reads Xt=d0) || th0 build (waves 1-15 -> Xb) =====
    if (wave == 0) {
        half8 aw[NKC];
#pragma unroll
        for (int kc = 0; kc < NKC; ++kc) aw[kc] = W0sw[kc*64 + lane];
        float4v g = (float4v){0.f,0.f,0.f,0.f};
#pragma unroll
        for (int kc = 0; kc < NKC; ++kc) {
            half8 x = *(const half8*)(Xt + lm*XSTR + kc*32 + q*8);
            g = __builtin_amdgcn_mfma_f32_16x16x32_f16(aw[kc], x, g, 0, 0, 0);
        }
        float4v gv; gv.x = g.x*INV_K; gv.y = g.y*INV_K; gv.z = g.z*INV_K; gv.w = g.w*INV_K;
        *(float4v*)(&gsh[lm*HSTR + q*4]) = gv;
    } else {
        for (int idx = tid - 64; idx < 128*50; idx += NTHREADS - 64) {
            int row = idx / 50, u = (idx % 50)*4;
            int s = row & 15, t = row >> 4;
            half4v p0 = *(const half4v*)(&Cf[0][s*CSTR + u]);
            half4v w0 = *(const half4v*)(&w0t[t*WSTR + u]);
            *(half4v*)(&Xb[row*XSTR + u]) = p0 * w0;
        }
    }
    __syncthreads();

    // ========== T-phase: 13 waves x 1 m-tile x 8 n-tiles, pure ping-pong ==========
    float4v acc8[1][NT8];
    half4v c3th1[NT8];           // c3 * th1' carried T2 -> T4 in registers

    // T2: reads Xb(th0) -> th1'->Xt ; carry c3*th1'
    if (wave < NMT) {
        run_mv<NT8,1>(W1Tsw, Xb, wave, lane, acc8);
        half4v p1 = *(const half4v*)(&Cf[1][lm*CSTR + ubf]);
        half4v c3 = *(const half4v*)(&Cf[3][lm*CSTR + ubf]);
#pragma unroll
        for (int n = 0; n < NT8; ++n) {
            half4v t = pk4(acc8[0][n]) * p1;
            *(half4v*)(&Xt[(n*16 + lm)*XSTR + ubf]) = t;
            c3th1[n] = c3 * t;
        }
    }
    __syncthreads();

    // T3: reads Xt(th1') -> d2dot->Xb
    if (wave < NMT) {
        run_mv<NT8,1>(W2Tsw, Xt, wave, lane, acc8);
        half4v c2 = *(const half4v*)(&Cf[2][lm*CSTR + ubf]);
#pragma unroll
        for (int n = 0; n < NT8; ++n)
            *(half4v*)(&Xb[(n*16 + lm)*XSTR + ubf]) = pk4(acc8[0][n]) * c2;
    }
    __syncthreads();

    // T4: reads Xb(d2dot) -> d1dot = v1''*p1 + c3*th1' -> Xt (th1' dead)
    if (wave < NMT) {
        run_mv<NT8,1>(W2sw, Xb, wave, lane, acc8);
        half4v p1 = *(const half4v*)(&Cf[1][lm*CSTR + ubf]);
#pragma unroll
        for (int n = 0; n < NT8; ++n)
            *(half4v*)(&Xt[(n*16 + lm)*XSTR + ubf]) = pk4(acc8[0][n]) * p1 + c3th1[n];
    }
    __syncthreads();

    // T5: reads Xt(d1dot) -> d0dot = v0''*p0 + c4*(S*t0) -> Xb (d2dot dead)
    if (wave < NMT) {
        run_mv<NT8,1>(W1sw, Xt, wave, lane, acc8);
        half4v p0 = *(const half4v*)(&Cf[0][lm*CSTR + ubf]);
        half4v c4 = *(const half4v*)(&Cf[4][lm*CSTR + ubf]);
#pragma unroll
        for (int n = 0; n < NT8; ++n) {
            half4v w0 = *(const half4v*)(&w0t[n*WSTR + ubf]);
            *(half4v*)(&Xb[(n*16 + lm)*XSTR + ubf]) = pk4(acc8[0][n]) * p0 + c4 * w0;
        }
    }
    __syncthreads();

    // ========= Hr projection: waves 0-7, nt = wave (reads Xb=d0dot) =========
    if (wave < 8) {
        half8 aw[NKC];
#pragma unroll
        for (int kc = 0; kc < NKC; ++kc) aw[kc] = W0sw[kc*64 + lane];
        float4v hacc = (float4v){0.f,0.f,0.f,0.f};
#pragma unroll
        for (int kc = 0; kc < NKC; ++kc) {
            half8 x = *(const half8*)(Xb + (wave*16 + lm)*XSTR + kc*32 + q*8);
            hacc = __builtin_amdgcn_mfma_f32_16x16x32_f16(aw[kc], x, hacc, 0, 0, 0);
        }
        int row = wave*16 + lm;
        float4v hv;
        hv.x = hacc.x*INV_KS; hv.y = hacc.y*INV_KS;
        hv.z = hacc.z*INV_KS; hv.w = hacc.w*INV_KS;
        *(float4v*)(&Hr[row*HSTR + q*4]) = hv;
    }
    __syncthreads();

    // ========= per-sample 8x8 solve =========
    if (tid < BS) {
        const int s = tid;
        float M[DD][DD], F[DD], v[DD], a[DD];
#pragma unroll
        for (int c = 0; c < DD; ++c) v[c] = z[(s0 + s)*ZD + DD + c];
#pragma unroll
        for (int r = 0; r < DD; ++r) {
            float f = gsh[s*HSTR + r];
#pragma unroll
            for (int c = 0; c < DD; ++c) {
                M[r][c] = Hr[(r*16 + s)*HSTR + DD + c] + ((r == c) ? 2.f*EPSL : 0.f);
                f -= Hr[(r*16 + s)*HSTR + c] * v[c];
            }
            F[r] = f;
        }
#pragma unroll
        for (int col = 0; col < DD; ++col) {
            const float inv = 1.f / M[col][col];
#pragma unroll
            for (int r = col + 1; r < DD; ++r) {
                const float fac = M[r][col] * inv;
#pragma unroll
                for (int c = col + 1; c < DD; ++c) M[r][c] -= fac * M[col][c];
                F[r] -= fac * F[col];
            }
        }
#pragma unroll
        for (int r = DD - 1; r >= 0; --r) {
            float ssum = F[r];
#pragma unroll
            for (int c = r + 1; c < DD; ++c) ssum -= M[r][c] * a[c];
            a[r] = ssum / M[r][r];
        }
        float* op = out + (size_t)(s0 + s)*ZD;
#pragma unroll
        for (int c = 0; c < DD; ++c) { op[c] = v[c]; op[DD + c] = a[c]; }
    }
}

extern "C" void kernel_launch(void* const* d_in, const int* in_sizes, int n_in,
                              void* d_out, int out_size, void* d_ws, size_t ws_size,
                              hipStream_t stream)
{
    const float* z  = (const float*)d_in[1];
    const float* W0 = (const float*)d_in[2];
    const float* b0 = (const float*)d_in[3];
    const float* W1 = (const float*)d_in[4];
    const float* b1 = (const float*)d_in[5];
    const float* W2 = (const float*)d_in[6];
    const float* b2 = (const float*)d_in[7];
    const float* W3 = (const float*)d_in[8];
    float* out = (float*)d_out;
    _Float16* ws = (_Float16*)d_ws;

    const int n = in_sizes[1] / (2*DD);

    prep<<<dim3((WS_HALFS + 255)/256), dim3(256), 0, stream>>>(W0, W1, W2, ws);
    lnn_main<<<dim3(n / BS), dim3(NTHREADS), 0, stream>>>(
        z, W0, b0, b1, b2, W3, ws, out);
}

// Round 9
// 166.912 us; speedup vs baseline: 1.0327x; 1.0327x over previous
//
#include <hip/hip_runtime.h>
#include <math.h>

#define DD 8
#define ZD 16
#define HID 200
#define EPSL 0.1f
#define BS 8           // samples per block
#define NTHREADS 512   // 8 waves; 2 blocks/CU (LDS < 80 KB)
#define NKC 7          // K chunks of 32 (200 -> 224)
#define NMT 13         // unit tiles of 16 (200 -> 208)
#define XSTR 200       // halfs per X row: 100 dw = 4 mod 32 (2-way), 16B-aligned
#define CSTR 208       // halfs per coeff row
#define WSTR 208       // halfs per staged-weight row
#define NTAN 8
#define NT4 4          // n-tiles per wave in T phase (64 rows = 8 tan x 8 samples)

#define KSC 1024.0f        // backward-chain scale
#define SSC 64.0f          // tangent-chain scale
#define INV_K (1.0f/1024.0f)
#define INV_KS (1.0f/65536.0f)

typedef _Float16 half8 __attribute__((ext_vector_type(8)));
typedef _Float16 half4v __attribute__((ext_vector_type(4)));
typedef _Float16 half2v __attribute__((ext_vector_type(2)));
typedef float float4v __attribute__((ext_vector_type(4)));

#define S4 (NKC*NMT*64*8)
#define OFF_W1T 0
#define OFF_W2T (S4)
#define OFF_W1  (2*S4)
#define OFF_W2  (3*S4)
#define OFF_W0T (4*S4)
#define OFF_W0  (4*S4 + NMT*64*8)
#define WS_HALFS (4*S4 + NMT*64*8 + NKC*64*8)

// ---------------------------------------------------------------------------
__global__ void prep(const float* __restrict__ W0, const float* __restrict__ W1,
                     const float* __restrict__ W2, _Float16* __restrict__ ws)
{
    int idx = blockIdx.x * 256 + threadIdx.x;
    if (idx >= WS_HALFS) return;
    float v = 0.f;
    if (idx < 4*S4) {
        int arr = idx / S4, e = idx % S4;
        int kc = e / (NMT*64*8); int r = e % (NMT*64*8);
        int mt = r / (64*8); r %= 64*8;
        int lane = r / 8, j = r % 8;
        int m = mt*16 + (lane & 15);
        int k = kc*32 + (lane >> 4)*8 + j;
        if (m < HID && k < HID) {
            if      (arr == 0) v = W1[k*HID + m];
            else if (arr == 1) v = W2[k*HID + m];
            else if (arr == 2) v = W1[m*HID + k];
            else               v = W2[m*HID + k];
        }
    } else if (idx < OFF_W0) {
        int e = idx - OFF_W0T;
        int mt = e / (64*8); int r = e % (64*8);
        int lane = r / 8, j = r % 8;
        int m = mt*16 + (lane & 15);
        int k = (lane >> 4)*8 + j;
        if (m < HID && k < ZD) v = W0[k*HID + m];
    } else {
        int e = idx - OFF_W0;
        int kc = e / (64*8); int r = e % (64*8);
        int lane = r / 8, j = r % 8;
        int m = (lane & 15);
        int k = kc*32 + (lane >> 4)*8 + j;
        if (k < HID) v = W0[m*HID + k];
    }
    ws[idx] = (_Float16)v;
}

// ---------------------------------------------------------------------------
__device__ __forceinline__ half4v pk4(float4v a) {
    half2v lo = __builtin_bit_cast(half2v, __builtin_amdgcn_cvt_pkrtz(a.x, a.y));
    half2v hi = __builtin_bit_cast(half2v, __builtin_amdgcn_cvt_pkrtz(a.z, a.w));
    return __builtin_shufflevector(lo, hi, 0, 1, 2, 3);
}
__device__ __forceinline__ void sig_sp(float x, float& sp, float& sg) {
    float e = __expf(-fabsf(x));
    float r = 1.0f / (1.0f + e);
    sg = (x >= 0.f) ? r : (1.0f - r);
    sp = fmaxf(x, 0.f) + __logf(1.f + e);
}

// Matvec over 7 K-chunks, MTC m-tiles x NTILES n-tiles.
// X rows are XSTR=200 halfs; reads with k>=200 spill into the next row's
// real data -- finite, and A=0 for k>=200 nullifies the products.
template<int NTILES, int MTC>
__device__ __forceinline__ void run_mv(const half8* __restrict__ Asw,
                                       const _Float16* __restrict__ Xsrc,
                                       int mt0, int lane,
                                       float4v acc[MTC][NTILES])
{
    const int lm = lane & 15, q = lane >> 4;
    constexpr int PF = (NTILES > 1) ? 2 : NKC;
#pragma unroll
    for (int m = 0; m < MTC; ++m)
#pragma unroll
        for (int n = 0; n < NTILES; ++n)
            acc[m][n] = (float4v){0.f, 0.f, 0.f, 0.f};

    half8 a[MTC][PF];
#pragma unroll
    for (int p = 0; p < PF; ++p)
#pragma unroll
        for (int m = 0; m < MTC; ++m)
            a[m][p] = Asw[(p*NMT + mt0 + m)*64 + lane];

#pragma unroll
    for (int kc = 0; kc < NKC; ++kc) {
        half8 x[NTILES];
#pragma unroll
        for (int n = 0; n < NTILES; ++n)
            x[n] = *(const half8*)(Xsrc + (n*16 + lm)*XSTR + kc*32 + q*8);
        half8 an[MTC];
        if (kc + PF < NKC)
#pragma unroll
            for (int m = 0; m < MTC; ++m)
                an[m] = Asw[((kc+PF)*NMT + mt0 + m)*64 + lane];
#pragma unroll
        for (int m = 0; m < MTC; ++m)
#pragma unroll
            for (int n = 0; n < NTILES; ++n)
                acc[m][n] = __builtin_amdgcn_mfma_f32_16x16x32_f16(a[m][0], x[n], acc[m][n], 0, 0, 0);
#pragma unroll
        for (int m = 0; m < MTC; ++m)
#pragma unroll
            for (int p = 0; p + 1 < PF; ++p) a[m][p] = a[m][p+1];
        if (kc + PF < NKC)
#pragma unroll
            for (int m = 0; m < MTC; ++m) a[m][PF-1] = an[m];
    }
}

// ---------------------------------------------------------------------------
__global__ void __launch_bounds__(NTHREADS, 4)
lnn_main(const float* __restrict__ z,
         const float* __restrict__ W0, const float* __restrict__ b0,
         const float* __restrict__ b1, const float* __restrict__ b2,
         const float* __restrict__ W3,
         const _Float16* __restrict__ ws,
         float* __restrict__ out)
{
    __shared__ alignas(16) _Float16 Xt[64*XSTR + 24];
    __shared__ alignas(16) _Float16 Xb[64*XSTR + 24];
    __shared__ alignas(16) _Float16 Cf[5][8*CSTR]; // 0:p0 1:p1 2:c2*K 3:u1'(1-p1) 4:u0'p0(1-p0)
    __shared__ alignas(16) _Float16 Xz[16*32];
    __shared__ alignas(16) _Float16 bsh[4*WSTR];    // b0,b1,b2,KSC*W3 (zero-padded)
    __shared__ alignas(16) _Float16 w0t[NTAN*WSTR]; // SSC*W0[8+t][u] (zero-padded)
    __shared__ alignas(16) float gsh[8*16];         // [sample][z]
    __shared__ alignas(16) float Hr[64*16];         // [t*8+s][z]

    const int tid  = threadIdx.x;
    const int wave = tid >> 6;
    const int lane = tid & 63;
    const int lm   = lane & 15;
    const int q    = lane >> 4;
    const int s0   = blockIdx.x * BS;

    // m-split over 8 waves: {2,2,2,2,2,1,1,1} (13 m-tiles)
    const int mt0 = (wave < 5) ? wave*2 : (10 + (wave - 5));
    const int mtc = (wave < 5) ? 2 : 1;

    const half8* W1Tsw = (const half8*)(ws + OFF_W1T);
    const half8* W2Tsw = (const half8*)(ws + OFF_W2T);
    const half8* W1sw  = (const half8*)(ws + OFF_W1);
    const half8* W2sw  = (const half8*)(ws + OFF_W2);
    const half8* W0Tsw = (const half8*)(ws + OFF_W0T);
    const half8* W0sw  = (const half8*)(ws + OFF_W0);

    // ---- init/staging ----
    for (int idx = tid; idx < 16*32; idx += NTHREADS) {
        int s = idx >> 5, c = idx & 31;
        Xz[idx] = (s < BS && c < ZD) ? (_Float16)z[(s0 + s)*ZD + c] : (_Float16)0.f;
    }
    // F-phase row-15 overrun reads rows 16 cols 0..23 (uninit until th0);
    // row-63 overrun reads the tail. Zero both, both arrays.
    if (tid < 24) {
        Xt[16*XSTR + tid] = (_Float16)0.f;
        Xb[16*XSTR + tid] = (_Float16)0.f;
        Xt[64*XSTR + tid] = (_Float16)0.f;
        Xb[64*XSTR + tid] = (_Float16)0.f;
    }
    for (int idx = tid; idx < 4*WSTR; idx += NTHREADS) {
        int l = idx / WSTR, u = idx % WSTR;
        float v = 0.f;
        if (u < HID) {
            if      (l == 0) v = b0[u];
            else if (l == 1) v = b1[u];
            else if (l == 2) v = b2[u];
            else             v = KSC * W3[u];
        }
        bsh[idx] = (_Float16)v;
    }
    for (int idx = tid; idx < NTAN*WSTR; idx += NTHREADS) {
        int t = idx / WSTR, u = idx % WSTR;
        w0t[idx] = (_Float16)((u < HID) ? SSC * W0[(DD + t)*HID + u] : 0.f);
    }
    __syncthreads();

    float4v acc1[2][1];

    // ========== F-phase: Xt/Xb ping-pong, one barrier per stage ==========
    // F0: a0 = z@W0+b0 ; h0->Xt, p0->Cf0
    {
        half8 xz = *(const half8*)(Xz + lm*32 + q*8);
#pragma unroll
        for (int m = 0; m < 2; ++m)
            if (m < mtc) {
                acc1[m][0] = (float4v){0.f,0.f,0.f,0.f};
                half8 a = W0Tsw[(mt0 + m)*64 + lane];
                acc1[m][0] = __builtin_amdgcn_mfma_f32_16x16x32_f16(a, xz, acc1[m][0], 0, 0, 0);
                const int ub = (mt0 + m)*16 + q*4;
                const bool padq = (mt0 + m == 12) && (q >= 2);
                half4v bb = *(const half4v*)(&bsh[0*WSTR + ub]);
                float h[4], p[4];
#pragma unroll
                for (int r = 0; r < 4; ++r) {
                    float av = acc1[m][0][r] + (float)bb[r];
                    sig_sp(av, h[r], p[r]);
                }
                if (!padq) *(half4v*)(&Xt[lm*XSTR + ub]) = pk4((float4v){h[0],h[1],h[2],h[3]});
                if (lm < BS) *(half4v*)(&Cf[0][lm*CSTR + ub]) = pk4((float4v){p[0],p[1],p[2],p[3]});
            }
    }
    __syncthreads();

    // F1: reads Xt(h0) -> h1->Xb, p1->Cf1
    {
        if (mtc == 2) run_mv<1,2>(W1Tsw, Xt, mt0, lane, acc1);
        else          run_mv<1,1>(W1Tsw, Xt, mt0, lane, acc1);
#pragma unroll
        for (int m = 0; m < 2; ++m)
            if (m < mtc) {
                const int ub = (mt0 + m)*16 + q*4;
                const bool padq = (mt0 + m == 12) && (q >= 2);
                half4v bb = *(const half4v*)(&bsh[1*WSTR + ub]);
                float h[4], p[4];
#pragma unroll
                for (int r = 0; r < 4; ++r) {
                    float av = acc1[m][0][r] + (float)bb[r];
                    sig_sp(av, h[r], p[r]);
                }
                if (!padq) *(half4v*)(&Xb[lm*XSTR + ub]) = pk4((float4v){h[0],h[1],h[2],h[3]});
                if (lm < BS) *(half4v*)(&Cf[1][lm*CSTR + ub]) = pk4((float4v){p[0],p[1],p[2],p[3]});
            }
    }
    __syncthreads();

    // F2: reads Xb(h1) -> d2'->Xt, c2'->Cf2
    {
        if (mtc == 2) run_mv<1,2>(W2Tsw, Xb, mt0, lane, acc1);
        else          run_mv<1,1>(W2Tsw, Xb, mt0, lane, acc1);
#pragma unroll
        for (int m = 0; m < 2; ++m)
            if (m < mtc) {
                const int ub = (mt0 + m)*16 + q*4;
                const bool padq = (mt0 + m == 12) && (q >= 2);
                half4v bb = *(const half4v*)(&bsh[2*WSTR + ub]);
                half4v w3 = *(const half4v*)(&bsh[3*WSTR + ub]);
                float d2[4], c2[4];
#pragma unroll
                for (int r = 0; r < 4; ++r) {
                    float av = acc1[m][0][r] + (float)bb[r];
                    float e = __expf(-fabsf(av));
                    float rr = 1.f / (1.f + e);
                    float sg = (av >= 0.f) ? rr : (1.f - rr);
                    float wk = (float)w3[r];
                    d2[r] = wk * sg;
                    c2[r] = wk * sg * (1.f - sg);
                }
                if (!padq) *(half4v*)(&Xt[lm*XSTR + ub]) = pk4((float4v){d2[0],d2[1],d2[2],d2[3]});
                if (lm < BS) *(half4v*)(&Cf[2][lm*CSTR + ub]) = pk4((float4v){c2[0],c2[1],c2[2],c2[3]});
            }
    }
    __syncthreads();

    // B1: reads Xt(d2') -> d1'->Xb, Cf3=u1'(1-p1)
    {
        if (mtc == 2) run_mv<1,2>(W2sw, Xt, mt0, lane, acc1);
        else          run_mv<1,1>(W2sw, Xt, mt0, lane, acc1);
#pragma unroll
        for (int m = 0; m < 2; ++m)
            if (m < mtc) {
                const int ub = (mt0 + m)*16 + q*4;
                const bool padq = (mt0 + m == 12) && (q >= 2);
                half4v p1 = *(const half4v*)(&Cf[1][(lm & 7)*CSTR + ub]);
                half4v u1 = pk4(acc1[m][0]);
                half4v one = {(_Float16)1.f,(_Float16)1.f,(_Float16)1.f,(_Float16)1.f};
                if (!padq) *(half4v*)(&Xb[lm*XSTR + ub]) = u1 * p1;
                if (lm < BS) *(half4v*)(&Cf[3][lm*CSTR + ub]) = u1 * (one - p1);
            }
    }
    __syncthreads();

    // B0: reads Xb(d1') -> d0'->Xt, Cf4=u0'p0(1-p0)
    {
        if (mtc == 2) run_mv<1,2>(W1sw, Xb, mt0, lane, acc1);
        else          run_mv<1,1>(W1sw, Xb, mt0, lane, acc1);
#pragma unroll
        for (int m = 0; m < 2; ++m)
            if (m < mtc) {
                const int ub = (mt0 + m)*16 + q*4;
                const bool padq = (mt0 + m == 12) && (q >= 2);
                half4v p0 = *(const half4v*)(&Cf[0][(lm & 7)*CSTR + ub]);
                half4v u0 = pk4(acc1[m][0]);
                half4v one = {(_Float16)1.f,(_Float16)1.f,(_Float16)1.f,(_Float16)1.f};
                half4v d0 = u0 * p0;
                if (!padq) *(half4v*)(&Xt[lm*XSTR + ub]) = d0;
                if (lm < BS) *(half4v*)(&Cf[4][lm*CSTR + ub]) = d0 * (one - p0);
            }
    }
    __syncthreads();

    // ===== g-projection (wave 0, reads Xt=d0) || th0 build (waves 1-7 -> Xb rows 0..63) =====
    if (wave == 0) {
        half8 aw[NKC];
#pragma unroll
        for (int kc = 0; kc < NKC; ++kc) aw[kc] = W0sw[kc*64 + lane];
        float4v g = (float4v){0.f,0.f,0.f,0.f};
#pragma unroll
        for (int kc = 0; kc < NKC; ++kc) {
            half8 x = *(const half8*)(Xt + lm*XSTR + kc*32 + q*8);
            g = __builtin_amdgcn_mfma_f32_16x16x32_f16(aw[kc], x, g, 0, 0, 0);
        }
        if (lm < BS) {
            float4v gv; gv.x = g.x*INV_K; gv.y = g.y*INV_K; gv.z = g.z*INV_K; gv.w = g.w*INV_K;
            *(float4v*)(&gsh[lm*16 + q*4]) = gv;
        }
    } else {
        for (int idx = tid - 64; idx < 64*50; idx += NTHREADS - 64) {
            int row = idx / 50, u = (idx % 50)*4;
            int s = row & 7, t = row >> 3;
            half4v p0 = *(const half4v*)(&Cf[0][s*CSTR + u]);
            half4v w0 = *(const half4v*)(&w0t[t*WSTR + u]);
            *(half4v*)(&Xb[row*XSTR + u]) = p0 * w0;
        }
    }
    __syncthreads();

    // ========== T-phase: 8 waves x mtc m-tiles x 4 n-tiles, pure ping-pong ==========
    float4v acc4[2][NT4];
    half4v c3th1[2][NT4];   // c3 * th1' carried T2 -> T4 in registers

    // T2: reads Xb(th0) -> th1'->Xt ; carry c3*th1'
    {
        if (mtc == 2) run_mv<NT4,2>(W1Tsw, Xb, mt0, lane, acc4);
        else          run_mv<NT4,1>(W1Tsw, Xb, mt0, lane, acc4);
#pragma unroll
        for (int m = 0; m < 2; ++m)
            if (m < mtc) {
                const int ub = (mt0 + m)*16 + q*4;
                const bool padq = (mt0 + m == 12) && (q >= 2);
                half4v p1 = *(const half4v*)(&Cf[1][(lm & 7)*CSTR + ub]);
                half4v c3 = *(const half4v*)(&Cf[3][(lm & 7)*CSTR + ub]);
#pragma unroll
                for (int n = 0; n < NT4; ++n) {
                    half4v t = pk4(acc4[m][n]) * p1;
                    if (!padq) *(half4v*)(&Xt[(n*16 + lm)*XSTR + ub]) = t;
                    c3th1[m][n] = c3 * t;
                }
            }
    }
    __syncthreads();

    // T3: reads Xt(th1') -> d2dot->Xb
    {
        if (mtc == 2) run_mv<NT4,2>(W2Tsw, Xt, mt0, lane, acc4);
        else          run_mv<NT4,1>(W2Tsw, Xt, mt0, lane, acc4);
#pragma unroll
        for (int m = 0; m < 2; ++m)
            if (m < mtc) {
                const int ub = (mt0 + m)*16 + q*4;
                const bool padq = (mt0 + m == 12) && (q >= 2);
                half4v c2 = *(const half4v*)(&Cf[2][(lm & 7)*CSTR + ub]);
#pragma unroll
                for (int n = 0; n < NT4; ++n)
                    if (!padq) *(half4v*)(&Xb[(n*16 + lm)*XSTR + ub]) = pk4(acc4[m][n]) * c2;
            }
    }
    __syncthreads();

    // T4: reads Xb(d2dot) -> d1dot = v1''*p1 + c3*th1' -> Xt
    {
        if (mtc == 2) run_mv<NT4,2>(W2sw, Xb, mt0, lane, acc4);
        else          run_mv<NT4,1>(W2sw, Xb, mt0, lane, acc4);
#pragma unroll
        for (int m = 0; m < 2; ++m)
            if (m < mtc) {
                const int ub = (mt0 + m)*16 + q*4;
                const bool padq = (mt0 + m == 12) && (q >= 2);
                half4v p1 = *(const half4v*)(&Cf[1][(lm & 7)*CSTR + ub]);
#pragma unroll
                for (int n = 0; n < NT4; ++n)
                    if (!padq) *(half4v*)(&Xt[(n*16 + lm)*XSTR + ub]) = pk4(acc4[m][n]) * p1 + c3th1[m][n];
            }
    }
    __syncthreads();

    // T5: reads Xt(d1dot) -> d0dot = v0''*p0 + c4*(S*t0) -> Xb
    {
        if (mtc == 2) run_mv<NT4,2>(W1sw, Xt, mt0, lane, acc4);
        else          run_mv<NT4,1>(W1sw, Xt, mt0, lane, acc4);
#pragma unroll
        for (int m = 0; m < 2; ++m)
            if (m < mtc) {
                const int ub = (mt0 + m)*16 + q*4;
                const bool padq = (mt0 + m == 12) && (q >= 2);
                half4v p0 = *(const half4v*)(&Cf[0][(lm & 7)*CSTR + ub]);
                half4v c4 = *(const half4v*)(&Cf[4][(lm & 7)*CSTR + ub]);
#pragma unroll
                for (int n = 0; n < NT4; ++n) {
                    int t = n*2 + (lm >> 3);
                    half4v w0 = *(const half4v*)(&w0t[t*WSTR + ub]);
                    if (!padq) *(half4v*)(&Xb[(n*16 + lm)*XSTR + ub]) = pk4(acc4[m][n]) * p0 + c4 * w0;
                }
            }
    }
    __syncthreads();

    // ========= Hr projection: waves 0-3, nt = wave (reads Xb=d0dot) =========
    if (wave < 4) {
        half8 aw[NKC];
#pragma unroll
        for (int kc = 0; kc < NKC; ++kc) aw[kc] = W0sw[kc*64 + lane];
        float4v hacc = (float4v){0.f,0.f,0.f,0.f};
#pragma unroll
        for (int kc = 0; kc < NKC; ++kc) {
            half8 x = *(const half8*)(Xb + (wave*16 + lm)*XSTR + kc*32 + q*8);
            hacc = __builtin_amdgcn_mfma_f32_16x16x32_f16(aw[kc], x, hacc, 0, 0, 0);
        }
        int row = wave*16 + lm;   // = t*8 + s
        float4v hv;
        hv.x = hacc.x*INV_KS; hv.y = hacc.y*INV_KS;
        hv.z = hacc.z*INV_KS; hv.w = hacc.w*INV_KS;
        *(float4v*)(&Hr[row*16 + q*4]) = hv;
    }
    __syncthreads();

    // ========= per-sample 8x8 solve =========
    if (tid < BS) {
        const int s = tid;
        float M[DD][DD], F[DD], v[DD], a[DD];
#pragma unroll
        for (int c = 0; c < DD; ++c) v[c] = z[(s0 + s)*ZD + DD + c];
#pragma unroll
        for (int r = 0; r < DD; ++r) {
            float f = gsh[s*16 + r];
#pragma unroll
            for (int c = 0; c < DD; ++c) {
                M[r][c] = Hr[(r*8 + s)*16 + DD + c] + ((r == c) ? 2.f*EPSL : 0.f);
                f -= Hr[(r*8 + s)*16 + c] * v[c];
            }
            F[r] = f;
        }
#pragma unroll
        for (int col = 0; col < DD; ++col) {
            const float inv = 1.f / M[col][col];
#pragma unroll
            for (int r = col + 1; r < DD; ++r) {
                const float fac = M[r][col] * inv;
#pragma unroll
                for (int c = col + 1; c < DD; ++c) M[r][c] -= fac * M[col][c];
                F[r] -= fac * F[col];
            }
        }
#pragma unroll
        for (int r = DD - 1; r >= 0; --r) {
            float ssum = F[r];
#pragma unroll
            for (int c = r + 1; c < DD; ++c) ssum -= M[r][c] * a[c];
            a[r] = ssum / M[r][r];
        }
        float* op = out + (size_t)(s0 + s)*ZD;
#pragma unroll
        for (int c = 0; c < DD; ++c) { op[c] = v[c]; op[DD + c] = a[c]; }
    }
}

extern "C" void kernel_launch(void* const* d_in, const int* in_sizes, int n_in,
                              void* d_out, int out_size, void* d_ws, size_t ws_size,
                              hipStream_t stream)
{
    const float* z  = (const float*)d_in[1];
    const float* W0 = (const float*)d_in[2];
    const float* b0 = (const float*)d_in[3];
    const float* W1 = (const float*)d_in[4];
    const float* b1 = (const float*)d_in[5];
    const float* W2 = (const float*)d_in[6];
    const float* b2 = (const float*)d_in[7];
    const float* W3 = (const float*)d_in[8];
    float* out = (float*)d_out;
    _Float16* ws = (_Float16*)d_ws;

    const int n = in_sizes[1] / (2*DD);

    prep<<<dim3((WS_HALFS + 255)/256), dim3(256), 0, stream>>>(W0, W1, W2, ws);
    lnn_main<<<dim3(n / BS), dim3(NTHREADS), 0, stream>>>(
        z, W0, b0, b1, b2, W3, ws, out);
}